// Round 1
// baseline (1747.119 us; speedup 1.0000x reference)
//
#include <hip/hip_runtime.h>

#define Bn 32
#define Cn 256
#define Hn 224
#define Wn 224
#define COn 256

// Kernel 1: compute shifted[b][rs][c] = bilinear sample of x[b,c] at the
// rs-th (of 9) deformable sample point. Only 36 pixels per (b,c) plane are
// ever touched -- we never read the full 1.6 GB x tensor.
__global__ __launch_bounds__(256) void deform_sample_kernel(
    const float* __restrict__ x, const float* __restrict__ offsets,
    float* __restrict__ sh)
{
    int t = blockIdx.x * 256 + threadIdx.x;
    if (t >= Bn * 9 * Cn) return;
    int c  = t & (Cn - 1);
    int rs = (t / Cn) % 9;
    int b  = t / (9 * Cn);
    int i = rs / 3, j = rs - i * 3;

    // grid[...,0] = gx = (i + off[i][j][0]) / (H-1); gx is the WIDTH coord
    // grid[...,1] = gy = (j + off[i][j][1]) / (H-1); gy is the HEIGHT coord
    float off0 = offsets[rs * 2 + 0];
    float off1 = offsets[rs * 2 + 1];
    float gx = ((float)i + off0) / 223.0f;
    float gy = ((float)j + off1) / 223.0f;
    // align_corners=False unnormalization
    float ix = ((gx + 1.0f) * 224.0f - 1.0f) * 0.5f;
    float iy = ((gy + 1.0f) * 224.0f - 1.0f) * 0.5f;
    float x0f = floorf(ix), y0f = floorf(iy);
    float wx1 = ix - x0f, wx0 = 1.0f - wx1;
    float wy1 = iy - y0f, wy0 = 1.0f - wy1;
    int x0 = (int)x0f, y0 = (int)y0f;
    int x1 = x0 + 1,   y1 = y0 + 1;

    const float* plane = x + (size_t)(b * Cn + c) * (Hn * Wn);
    bool vx0 = (x0 >= 0) & (x0 < Wn), vx1 = (x1 >= 0) & (x1 < Wn);
    bool vy0 = (y0 >= 0) & (y0 < Hn), vy1 = (y1 >= 0) & (y1 < Hn);
    float v00 = (vx0 & vy0) ? plane[y0 * Wn + x0] : 0.0f;
    float v10 = (vx1 & vy0) ? plane[y0 * Wn + x1] : 0.0f;
    float v01 = (vx0 & vy1) ? plane[y1 * Wn + x0] : 0.0f;
    float v11 = (vx1 & vy1) ? plane[y1 * Wn + x1] : 0.0f;

    float v = v00 * (wx0 * wy0) + v10 * (wx1 * wy0)
            + v01 * (wx0 * wy1) + v11 * (wx1 * wy1);
    sh[(b * 9 + rs) * Cn + c] = v;
}

// Kernel 2: 3x3 conv (pad 1) over the 3x3 "shifted" image.
// One block per (b, co); thread t == channel c. Stage w[co] (2304 floats)
// into LDS coalesced; each thread does the 49 valid FMAs for its channel;
// block-reduce the 9 outputs.
__global__ __launch_bounds__(256) void deform_conv_kernel(
    const float* __restrict__ sh, const float* __restrict__ w,
    const float* __restrict__ bias, float* __restrict__ out)
{
    int b  = blockIdx.x / COn;
    int co = blockIdx.x - b * COn;
    int t  = threadIdx.x;

    __shared__ float wl[Cn * 9];       // 9216 B
    __shared__ float partial[4][9];

    const float* wsrc = w + (size_t)co * Cn * 9;
    #pragma unroll
    for (int k = 0; k < 9; ++k)        // coalesced: 2304 contiguous floats
        wl[k * 256 + t] = wsrc[k * 256 + t];
    __syncthreads();

    float acc[9];
    #pragma unroll
    for (int k = 0; k < 9; ++k) acc[k] = 0.0f;

    const float* sp = sh + (size_t)b * 9 * Cn + t;   // coalesced per rs
    const float* wt = &wl[t * 9];      // stride 9 mod 32 -> 2 lanes/bank (free)

    #pragma unroll
    for (int r = 0; r < 3; ++r) {
        #pragma unroll
        for (int s = 0; s < 3; ++s) {
            float v = sp[(r * 3 + s) * Cn];
            #pragma unroll
            for (int p = 0; p < 3; ++p) {
                if (p < r - 1 || p > r + 1) continue;   // tap row valid
                #pragma unroll
                for (int q = 0; q < 3; ++q) {
                    if (q < s - 1 || q > s + 1) continue; // tap col valid
                    acc[p * 3 + q] += v * wt[(r - p + 1) * 3 + (s - q + 1)];
                }
            }
        }
    }

    int lane = t & 63, wv = t >> 6;
    #pragma unroll
    for (int k = 0; k < 9; ++k) {
        float v = acc[k];
        #pragma unroll
        for (int off = 32; off > 0; off >>= 1)
            v += __shfl_down(v, off, 64);
        if (lane == 0) partial[wv][k] = v;
    }
    __syncthreads();

    if (t < 9) {
        float s = partial[0][t] + partial[1][t] + partial[2][t] + partial[3][t]
                + bias[co];
        out[(size_t)(b * COn + co) * 9 + t] = s;
    }
}

extern "C" void kernel_launch(void* const* d_in, const int* in_sizes, int n_in,
                              void* d_out, int out_size, void* d_ws, size_t ws_size,
                              hipStream_t stream) {
    const float* x       = (const float*)d_in[0];
    const float* offsets = (const float*)d_in[1];
    const float* conv_w  = (const float*)d_in[2];
    const float* conv_b  = (const float*)d_in[3];
    float* out = (float*)d_out;
    float* sh  = (float*)d_ws;   // 32*9*256 floats = 294912 B

    int n1 = Bn * 9 * Cn;        // 73728 sample values
    deform_sample_kernel<<<(n1 + 255) / 256, 256, 0, stream>>>(x, offsets, sh);
    deform_conv_kernel<<<Bn * COn, 256, 0, stream>>>(sh, conv_w, conv_b, out);
}